// Round 12
// baseline (78.984 us; speedup 1.0000x reference)
//
#include <hip/hip_runtime.h>
#include <hip/hip_bf16.h>
#include <math.h>

// DotProductAttention B=32, L=2048, D=64, fp32 IO, per-batch key-length mask.
// Round 12: 2x2 wave decomposition to cut LDS read redundancy (the measured
// bottleneck: LDS pipe ~1090 cyc/block-k-tile > 850 cyc completion rate).
//  - Wave (wq,wk) = (wid>>1, wid&1) owns 32q x 32k of each 64x64 tile:
//    K-frag + V-frag LDS reads halve (4x -> 2x redundancy across waves).
//    MFMA/wave unchanged (8 QK^T + 8 PV, all 16x16x32 -- K=32 preserved).
//  - Per-wave private online softmax over its k-half; ONE epilogue
//    flash-merge per ticket via LDS (reuses K/V dbuf space, stride-65 pad).
//  - P path bit-identical to r6's proven layout/swizzle.
//  - Kept from r11: bf16 swizzled K/V tile images prepass, global_load_lds
//    DMA dbuf staging (1 barrier/tile), LPT queue, GRID 768.

#define BB 32
#define LL 2048
#define DD 64
#define QBLK 64
#define KBLK 64
#define NTILES (BB * (LL / QBLK))   // 1024
#define GRID 768

typedef __attribute__((ext_vector_type(8))) short bf16x8;
typedef __attribute__((ext_vector_type(4))) float f32x4;

static __device__ __forceinline__ short f2bf(float f) {
    __hip_bfloat16 h = __float2bfloat16(f);
    return *reinterpret_cast<short*>(&h);
}
static __device__ __forceinline__ unsigned pk2(float a, float b) {
    return (unsigned)(unsigned short)f2bf(a) | ((unsigned)(unsigned short)f2bf(b) << 16);
}
static __device__ __forceinline__ float exp2c(float x) {
    return __builtin_amdgcn_exp2f(x);
}
static __device__ __forceinline__ int kswz(int row) { return (row & 7) << 3; }
static __device__ __forceinline__ int vswz(int d)   { return ((d ^ (d >> 2)) & 7) << 3; }
static __device__ __forceinline__ int pswz(int row) { return (((row & 7) ^ (row >> 3)) & 7) << 3; }

static __device__ __forceinline__ void cp16(const unsigned short* g,
                                            unsigned short* lbase, int lane) {
#if __has_builtin(__builtin_amdgcn_global_load_lds)
    __builtin_amdgcn_global_load_lds(
        (__attribute__((address_space(1))) void*)g,
        (__attribute__((address_space(3))) void*)lbase, 16, 0, 0);
#else
    *reinterpret_cast<uint4*>(lbase + lane * 8) =
        *reinterpret_cast<const uint4*>(g);
#endif
}

// ws[0] = queue counter; ws[1..32] = batch ids sorted by valid_len desc (LPT)
__global__ void init_ctr_kernel(const int* __restrict__ vlen, int* __restrict__ ws) {
    int t = threadIdx.x;
    if (t == 0) ws[0] = 0;
    if (t < BB) {
        int v = vlen[t];
        int rank = 0;
        for (int j = 0; j < BB; ++j) {
            int vj = vlen[j];
            rank += (vj > v) || (vj == v && j < t);
        }
        ws[1 + rank] = t;
    }
}

// K,V fp32 -> bf16 tile images laid out exactly as the LDS buffers.
__global__ __launch_bounds__(256) void convert_kv_kernel(
    const float* __restrict__ K, const float* __restrict__ V,
    unsigned short* __restrict__ kv)
{
    const int tile = blockIdx.x;         // b*32 + kt
    const int tid  = threadIdx.x;
    const float*  Kt  = K + (size_t)tile * (KBLK * DD);
    const float4* Vg4 = reinterpret_cast<const float4*>(V + (size_t)tile * (KBLK * DD));
    unsigned short* img = kv + (size_t)tile * 8192;

    #pragma unroll
    for (int g = 0; g < 2; ++g) {
        int gi = tid + g * 256;
        int kr = gi >> 3;
        int dc = ((gi & 7) * 8) ^ kswz(kr);
        const float4* src = reinterpret_cast<const float4*>(Kt + kr * DD + dc);
        float4 a = src[0], c = src[1];
        uint4 w;
        w.x = pk2(a.x, a.y); w.y = pk2(a.z, a.w);
        w.z = pk2(c.x, c.y); w.w = pk2(c.z, c.w);
        *reinterpret_cast<uint4*>(img + (size_t)gi * 8) = w;
    }

    unsigned short* img2 = img + 4096;
    const int vd4 = (tid & 15) * 4;
    const int vkr = (tid >> 4) * 4;
    float4 v0 = Vg4[(vkr + 0) * 16 + (tid & 15)];
    float4 v1 = Vg4[(vkr + 1) * 16 + (tid & 15)];
    float4 v2 = Vg4[(vkr + 2) * 16 + (tid & 15)];
    float4 v3 = Vg4[(vkr + 3) * 16 + (tid & 15)];
    int e0 = ((vd4 + 0) * 64 + vkr) ^ vswz(vd4 + 0);
    *reinterpret_cast<uint2*>(img2 + e0) = make_uint2(pk2(v0.x, v1.x), pk2(v2.x, v3.x));
    int e1 = ((vd4 + 1) * 64 + vkr) ^ vswz(vd4 + 1);
    *reinterpret_cast<uint2*>(img2 + e1) = make_uint2(pk2(v0.y, v1.y), pk2(v2.y, v3.y));
    int e2 = ((vd4 + 2) * 64 + vkr) ^ vswz(vd4 + 2);
    *reinterpret_cast<uint2*>(img2 + e2) = make_uint2(pk2(v0.z, v1.z), pk2(v2.z, v3.z));
    int e3 = ((vd4 + 3) * 64 + vkr) ^ vswz(vd4 + 3);
    *reinterpret_cast<uint2*>(img2 + e3) = make_uint2(pk2(v0.w, v1.w), pk2(v2.w, v3.w));
}

__global__ __launch_bounds__(256, 2) void attn_mfma_kernel(
    const float* __restrict__ Q, const int* __restrict__ vlen,
    const unsigned short* __restrict__ kvimg,
    float* __restrict__ O, int* __restrict__ ws)
{
    __shared__ __align__(16) unsigned short Ks[2][KBLK * DD];   // [buf][k][d], kswz
    __shared__ __align__(16) unsigned short Vt[2][KBLK * DD];   // [buf][d][k], vswz
    __shared__ __align__(16) unsigned short Pl[4][16 * KBLK];   // per-wave P, pswz
    __shared__ float ml_sh[2][2][32];                           // [wq][{m,l}][q32]
    __shared__ int s_tile;

    int* ctr = ws;
    const int* order = ws + 1;

    const int tid  = threadIdx.x;
    const int wid  = tid >> 6;
    const int lane = tid & 63;
    const int lq   = lane & 15;
    const int lg   = lane >> 4;
    const int wq   = wid >> 1;      // q-half owner (0,1)
    const int wk   = wid & 1;       // k-half owner (0,1)

    const float QSCALE = 0.125f * 1.44269504088896341f;  // 1/sqrt(D) * log2(e)

    for (;;) {
        __syncthreads();
        if (tid == 0) s_tile = atomicAdd(ctr, 1);
        __syncthreads();
        const int tile = s_tile;
        if (tile >= NTILES) break;

        const int b     = order[tile >> 5];   // LPT: longest batches first
        const int qt    = tile & 31;
        const int qbw   = qt * QBLK + wq * 32;   // wave's 32-q base
        const int valid = vlen[b];
        const int ntiles = (valid + KBLK - 1) / KBLK;

        const unsigned short* tbase = kvimg + (size_t)b * (32 * 8192);

        auto load_tile = [&](int t, int buf) {
            const unsigned short* tp = tbase + (size_t)t * 8192 + wid * 512 + lane * 8;
            cp16(tp,        &Ks[buf][wid * 512],        lane);
            cp16(tp + 2048, &Ks[buf][2048 + wid * 512], lane);
            cp16(tp + 4096, &Vt[buf][wid * 512],        lane);
            cp16(tp + 6144, &Vt[buf][2048 + wid * 512], lane);
        };

        // ---- Q B-frags: qf[qsub][ds], q row = qbw + qsub*16 + lq
        bf16x8 qf[2][2];
        #pragma unroll
        for (int qsub = 0; qsub < 2; ++qsub) {
            const float* Qr = Q + ((size_t)b * LL + qbw + qsub * 16 + lq) * DD;
            #pragma unroll
            for (int ds_ = 0; ds_ < 2; ++ds_) {
                const float4* p4 = reinterpret_cast<const float4*>(Qr + ds_ * 32 + lg * 8);
                float4 a = p4[0], c = p4[1];
                bf16x8 f;
                f[0] = f2bf(a.x * QSCALE); f[1] = f2bf(a.y * QSCALE);
                f[2] = f2bf(a.z * QSCALE); f[3] = f2bf(a.w * QSCALE);
                f[4] = f2bf(c.x * QSCALE); f[5] = f2bf(c.y * QSCALE);
                f[6] = f2bf(c.z * QSCALE); f[7] = f2bf(c.w * QSCALE);
                qf[qsub][ds_] = f;
            }
        }

        f32x4 acc[2][4];   // acc[qsub][n][r]: q = qsub*16+lg*4+r, d = n*16+lq
        #pragma unroll
        for (int qsub = 0; qsub < 2; ++qsub)
            #pragma unroll
            for (int n = 0; n < 4; ++n) acc[qsub][n] = (f32x4){0.f, 0.f, 0.f, 0.f};
        float m_[2] = {-1e30f, -1e30f}, l_[2] = {0.f, 0.f};  // for q-col = lq

        load_tile(0, 0);
        __syncthreads();

        for (int kt = 0; kt < ntiles; ++kt) {
            const int cur = kt & 1;
            if (kt + 1 < ntiles) load_tile(kt + 1, cur ^ 1);

            // ---- K frags for this wave's k-half (shared across qsub)
            const unsigned short* ks = &Ks[cur][0];
            bf16x8 kf[2][2];
            #pragma unroll
            for (int ksub = 0; ksub < 2; ++ksub) {
                const int krow = wk * 32 + ksub * 16 + lq;
                #pragma unroll
                for (int ds_ = 0; ds_ < 2; ++ds_) {
                    int e = (krow * 64 + ds_ * 32 + lg * 8) ^ kswz(krow);
                    kf[ksub][ds_] = *reinterpret_cast<const bf16x8*>(&ks[e]);
                }
            }

            // ---- swapped QK^T: s[qsub][ksub][r] = S[k][q=col lq]
            f32x4 s[2][2];
            #pragma unroll
            for (int qsub = 0; qsub < 2; ++qsub)
                #pragma unroll
                for (int ksub = 0; ksub < 2; ++ksub) {
                    f32x4 a = (f32x4){0.f, 0.f, 0.f, 0.f};
                    a = __builtin_amdgcn_mfma_f32_16x16x32_bf16(kf[ksub][0], qf[qsub][0], a, 0, 0, 0);
                    a = __builtin_amdgcn_mfma_f32_16x16x32_bf16(kf[ksub][1], qf[qsub][1], a, 0, 0, 0);
                    s[qsub][ksub] = a;
                }

            // ---- mask (last tile only): k = kt*64 + wk*32 + ksub*16 + lg*4 + r
            const bool tail = (kt == ntiles - 1) && (valid & (KBLK - 1));
            if (tail) {
                const int kgb = kt * KBLK + wk * 32;
                #pragma unroll
                for (int qsub = 0; qsub < 2; ++qsub)
                    #pragma unroll
                    for (int ksub = 0; ksub < 2; ++ksub)
                        #pragma unroll
                        for (int r = 0; r < 4; ++r)
                            if (kgb + ksub * 16 + lg * 4 + r >= valid)
                                s[qsub][ksub][r] = -1e30f;
            }

            // ---- per-qsub row max: in-lane (8) + shfl over lg copies
            float mx[2];
            #pragma unroll
            for (int qsub = 0; qsub < 2; ++qsub) {
                float m8 = s[qsub][0][0];
                #pragma unroll
                for (int ksub = 0; ksub < 2; ++ksub)
                    #pragma unroll
                    for (int r = 0; r < 4; ++r) m8 = fmaxf(m8, s[qsub][ksub][r]);
                m8 = fmaxf(m8, __shfl_xor(m8, 16, 64));
                m8 = fmaxf(m8, __shfl_xor(m8, 32, 64));
                mx[qsub] = m8;
            }

            // ---- defer-max (T13, log2 domain THR=8)
            float grow = fmaxf(mx[0] - m_[0], mx[1] - m_[1]);
            if (__any(grow > 8.0f)) {
                #pragma unroll
                for (int qsub = 0; qsub < 2; ++qsub) {
                    float mnew = fmaxf(m_[qsub], mx[qsub]);
                    float corr = exp2c(m_[qsub] - mnew);
                    m_[qsub] = mnew;
                    l_[qsub] *= corr;
                    #pragma unroll
                    for (int r = 0; r < 4; ++r) {
                        float cq = __shfl(corr, lg * 4 + r, 64);
                        #pragma unroll
                        for (int n = 0; n < 4; ++n) acc[qsub][n][r] *= cq;
                    }
                }
            }

            // ---- p = exp2(s - m), sums
            #pragma unroll
            for (int qsub = 0; qsub < 2; ++qsub) {
                float ls = 0.f;
                #pragma unroll
                for (int ksub = 0; ksub < 2; ++ksub)
                    #pragma unroll
                    for (int r = 0; r < 4; ++r) {
                        float p = exp2c(s[qsub][ksub][r] - m_[qsub]);
                        s[qsub][ksub][r] = p;
                        ls += p;
                    }
                ls += __shfl_xor(ls, 16, 64);
                ls += __shfl_xor(ls, 32, 64);
                l_[qsub] += ls;
            }

            // ---- P -> wave-private LDS (r6's exact layout: t = qsub*2+ksub)
            unsigned short* Pw = &Pl[wid][0];
            #pragma unroll
            for (int qsub = 0; qsub < 2; ++qsub)
                #pragma unroll
                for (int ksub = 0; ksub < 2; ++ksub) {
                    int e = (lq * 64 + (qsub * 2 + ksub) * 16 + lg * 4) ^ pswz(lq);
                    *reinterpret_cast<uint2*>(&Pw[e]) =
                        make_uint2(pk2(s[qsub][ksub][0], s[qsub][ksub][1]),
                                   pk2(s[qsub][ksub][2], s[qsub][ksub][3]));
                }

            // ---- PV: vf shared across qsub (4 reads), K=32 per mfma
            const unsigned short* vt = &Vt[cur][0];
            bf16x8 vf[4];
            #pragma unroll
            for (int n = 0; n < 4; ++n) {
                int drow = n * 16 + lq;
                int ve = (drow * 64 + wk * 32 + lg * 8) ^ vswz(drow);
                vf[n] = *reinterpret_cast<const bf16x8*>(&vt[ve]);
            }
            #pragma unroll
            for (int qsub = 0; qsub < 2; ++qsub) {
                int pe = (lq * 64 + qsub * 32 + lg * 8) ^ pswz(lq);
                bf16x8 pf = *reinterpret_cast<const bf16x8*>(&Pw[pe]);
                #pragma unroll
                for (int n = 0; n < 4; ++n)
                    acc[qsub][n] = __builtin_amdgcn_mfma_f32_16x16x32_bf16(pf, vf[n], acc[qsub][n], 0, 0, 0);
            }

            __syncthreads();   // buf[cur^1] DMA complete; buf[cur] reads done
        }

        // ---- epilogue: flash-merge wk=1 partials into wk=0, write O
        float* mbuf = (wq == 0) ? (float*)&Ks[0][0] : (float*)&Vt[0][0];
        if (wk == 1) {
            #pragma unroll
            for (int qsub = 0; qsub < 2; ++qsub) {
                #pragma unroll
                for (int n = 0; n < 4; ++n)
                    #pragma unroll
                    for (int r = 0; r < 4; ++r) {
                        int ql = qsub * 16 + lg * 4 + r;
                        mbuf[ql * 65 + n * 16 + lq] = acc[qsub][n][r];
                    }
                if (lg == 0) {
                    ml_sh[wq][0][qsub * 16 + lq] = m_[qsub];
                    ml_sh[wq][1][qsub * 16 + lq] = l_[qsub];
                }
            }
        }
        __syncthreads();
        if (wk == 0) {
            float* Ob = O + ((size_t)b * LL + qbw) * DD;
            #pragma unroll
            for (int qsub = 0; qsub < 2; ++qsub) {
                #pragma unroll
                for (int r = 0; r < 4; ++r) {
                    int ql = qsub * 16 + lg * 4 + r;
                    float m0 = __shfl(m_[qsub], lg * 4 + r, 64);
                    float l0 = __shfl(l_[qsub], lg * 4 + r, 64);
                    float m1 = ml_sh[wq][0][ql];
                    float l1 = ml_sh[wq][1][ql];
                    float M  = fmaxf(m0, m1);
                    float w0 = exp2c(m0 - M), w1 = exp2c(m1 - M);
                    float inv = 1.f / (w0 * l0 + w1 * l1);
                    #pragma unroll
                    for (int n = 0; n < 4; ++n) {
                        float a1 = mbuf[ql * 65 + n * 16 + lq];
                        Ob[(size_t)ql * DD + n * 16 + lq] =
                            (w0 * acc[qsub][n][r] + w1 * a1) * inv;
                    }
                }
            }
        }
    }
}

extern "C" void kernel_launch(void* const* d_in, const int* in_sizes, int n_in,
                              void* d_out, int out_size, void* d_ws, size_t ws_size,
                              hipStream_t stream) {
    const float* Q = (const float*)d_in[0];
    const float* K = (const float*)d_in[1];
    const float* V = (const float*)d_in[2];
    const int* vlen = (const int*)d_in[3];
    float* O = (float*)d_out;

    int* ws_i = (int*)d_ws;
    unsigned short* kvimg = (unsigned short*)((char*)d_ws + 1024);

    init_ctr_kernel<<<1, 64, 0, stream>>>(vlen, ws_i);
    convert_kv_kernel<<<BB * (LL / KBLK), 256, 0, stream>>>(K, V, kvimg);
    attn_mfma_kernel<<<GRID, 256, 0, stream>>>(Q, vlen, kvimg, O, ws_i);
}

// Round 13
// 74.412 us; speedup vs baseline: 1.0614x; 1.0614x over previous
//
#include <hip/hip_runtime.h>
#include <hip/hip_bf16.h>
#include <math.h>

// DotProductAttention B=32, L=2048, D=64, fp32 IO, per-batch key-length mask.
// Round 13: break the per-tile serial chain (the invariant across r7-r12 nulls).
//  - PV via 16x16x16 MFMA (r8-verified mapping): A-frag = s packs in-register,
//    NO P-LDS roundtrip at all (removes 2 lgkm waits + conflicts).
//  - kvimg prepass stores K/V as the exact per-lane FRAGMENT sequence:
//    every ds_read_b128/b64 hits 64 consecutive slots -> conflict-free,
//    zero swizzle math. V frags (n,t)-ordered for the mfma16 B-operand.
//  - T15 2-deep pipeline, triple-buffered DMA, ONE barrier per tile:
//    [sync] -> DMA(t+2) -> QK^T(t+1) [MFMA pipe] -> softmax(t) [VALU] ->
//    PV(t) -> rotate. QK^T(t+1) overlaps softmax(t); DMA flies a full iter.
//    sA/sB named (unroll-2), buffer ids rotated by register moves.
//  - setprio(1) around MFMA clusters (T5). LPT queue + GRID 768 kept.

#define BB 32
#define LL 2048
#define DD 64
#define QBLK 64
#define KBLK 64
#define NTILES (BB * (LL / QBLK))   // 1024
#define GRID 768

typedef __attribute__((ext_vector_type(8))) short bf16x8;
typedef __attribute__((ext_vector_type(4))) short bf16x4;
typedef __attribute__((ext_vector_type(4))) float f32x4;

static __device__ __forceinline__ short f2bf(float f) {
    __hip_bfloat16 h = __float2bfloat16(f);
    return *reinterpret_cast<short*>(&h);
}
static __device__ __forceinline__ unsigned pk2(float a, float b) {
    return (unsigned)(unsigned short)f2bf(a) | ((unsigned)(unsigned short)f2bf(b) << 16);
}
static __device__ __forceinline__ float exp2c(float x) {
    return __builtin_amdgcn_exp2f(x);
}

static __device__ __forceinline__ f32x4 mfma16(bf16x4 a, bf16x4 b, f32x4 c) {
#if __has_builtin(__builtin_amdgcn_mfma_f32_16x16x16bf16_1k)
    return __builtin_amdgcn_mfma_f32_16x16x16bf16_1k(a, b, c, 0, 0, 0);
#else
    asm("v_mfma_f32_16x16x16_bf16 %0, %1, %2, %0" : "+v"(c) : "v"(a), "v"(b));
    return c;
#endif
}

// 16B global->LDS copy. Builtin: HW DMA, LDS dst = uniform base + lane*16.
static __device__ __forceinline__ void cp16(const char* g, char* lbase, int lane) {
#if __has_builtin(__builtin_amdgcn_global_load_lds)
    __builtin_amdgcn_global_load_lds(
        (__attribute__((address_space(1))) void*)g,
        (__attribute__((address_space(3))) void*)lbase, 16, 0, 0);
#else
    *reinterpret_cast<uint4*>(lbase + lane * 16) = *reinterpret_cast<const uint4*>(g);
#endif
}

// ws[0] = queue counter; ws[1..32] = batch ids sorted by valid_len desc (LPT)
__global__ void init_ctr_kernel(const int* __restrict__ vlen, int* __restrict__ ws) {
    int t = threadIdx.x;
    if (t == 0) ws[0] = 0;
    if (t < BB) {
        int v = vlen[t];
        int rank = 0;
        for (int j = 0; j < BB; ++j) {
            int vj = vlen[j];
            rank += (vj > v) || (vj == v && j < t);
        }
        ws[1 + rank] = t;
    }
}

// K,V fp32 -> bf16 FRAGMENT-ORDERED tile images (16KB per (b,kt) tile):
//  [0,8KB):  K-frags: entry e = (t*2+ds)*64 + L holds
//            K[t*16+(L&15)][ds*32+(L>>4)*8 .. +7]  (bf16x8, 16B)
//  [8,16KB): V-frags: entry = (n*4+t)*64 + L holds
//            V[t*16+(L>>4)*4 + {0..3}][n*16+(L&15)] (bf16x4, 8B, k-ascending)
__global__ __launch_bounds__(256) void convert_kv_kernel(
    const float* __restrict__ K, const float* __restrict__ V,
    unsigned short* __restrict__ kv)
{
    const int tile = blockIdx.x;         // b*32 + kt
    const int tid  = threadIdx.x;
    const float*  Kt  = K + (size_t)tile * (KBLK * DD);
    const float4* Vg4 = reinterpret_cast<const float4*>(V + (size_t)tile * (KBLK * DD));
    unsigned short* img = kv + (size_t)tile * 8192;   // 8192 shorts = 16KB

    // K-frags: 512 x 16B entries
    #pragma unroll
    for (int g = 0; g < 2; ++g) {
        int e = tid + g * 256;
        int f = e >> 6, L = e & 63;
        int t = f >> 1, ds = f & 1;
        int lq = L & 15, lg = L >> 4;
        const float4* src = reinterpret_cast<const float4*>(
            Kt + (t * 16 + lq) * DD + ds * 32 + lg * 8);
        float4 a = src[0], c = src[1];
        uint4 w;
        w.x = pk2(a.x, a.y); w.y = pk2(a.z, a.w);
        w.z = pk2(c.x, c.y); w.w = pk2(c.z, c.w);
        *reinterpret_cast<uint4*>(img + (size_t)e * 8) = w;
    }

    // V-frags: thread owns 4k x 4d block, writes 4 x 8B entries
    unsigned short* img2 = img + 4096;
    const int vd4 = (tid & 15) * 4;
    const int vkr = (tid >> 4) * 4;
    const int vt  = vkr >> 4;            // frag t
    const int vlg = (vkr >> 2) & 3;      // frag lg
    float4 v0 = Vg4[(vkr + 0) * 16 + (tid & 15)];
    float4 v1 = Vg4[(vkr + 1) * 16 + (tid & 15)];
    float4 v2 = Vg4[(vkr + 2) * 16 + (tid & 15)];
    float4 v3 = Vg4[(vkr + 3) * 16 + (tid & 15)];
    const float* p0 = (const float*)&v0;
    const float* p1 = (const float*)&v1;
    const float* p2 = (const float*)&v2;
    const float* p3 = (const float*)&v3;
    #pragma unroll
    for (int j = 0; j < 4; ++j) {
        int col = vd4 + j;
        int n = col >> 4, lq = col & 15;
        int L = vlg * 16 + lq;
        uint2 w = make_uint2(pk2(p0[j], p1[j]), pk2(p2[j], p3[j]));
        *reinterpret_cast<uint2*>(img2 + (size_t)(n * 4 + vt) * 256 + L * 4) = w;
    }
}

__global__ __launch_bounds__(256, 2) void attn_mfma_kernel(
    const float* __restrict__ Q, const int* __restrict__ vlen,
    const unsigned short* __restrict__ kvimg,
    float* __restrict__ O, int* __restrict__ ws)
{
    __shared__ __align__(16) unsigned short Buf[3][8192];   // 3 x 16KB (K|V frags)
    __shared__ int s_tile;

    int* ctr = ws;
    const int* order = ws + 1;

    const int tid  = threadIdx.x;
    const int wid  = tid >> 6;
    const int lane = tid & 63;
    const int lq   = lane & 15;
    const int lg   = lane >> 4;

    const float QSCALE = 0.125f * 1.44269504088896341f;  // 1/sqrt(D) * log2(e)

    for (;;) {
        __syncthreads();                 // prev ticket fully done before reuse
        if (tid == 0) s_tile = atomicAdd(ctr, 1);
        __syncthreads();
        const int tile = s_tile;
        if (tile >= NTILES) break;

        const int b     = order[tile >> 5];   // LPT: longest batches first
        const int qt    = tile & 31;
        const int qbase = qt * QBLK + wid * 16;
        const int valid = vlen[b];
        const int ntiles = (valid + KBLK - 1) / KBLK;

        const unsigned short* tbase = kvimg + (size_t)b * (32 * 8192);

        // stage tile t (16KB image) into Buf[bi]: 4 x cp16 per thread
        auto dma = [&](int t, int bi) {
            const char* g = (const char*)(tbase + (size_t)t * 8192)
                            + wid * 4096 + lane * 16;
            char* l = (char*)&Buf[bi][0] + wid * 4096;
            cp16(g,        l,        lane);
            cp16(g + 1024, l + 1024, lane);
            cp16(g + 2048, l + 2048, lane);
            cp16(g + 3072, l + 3072, lane);
        };

        // ---- Q B-frags (regs): lane holds Q[qbase+lq][ds*32 + lg*8 .. +7]
        bf16x8 qf[2];
        {
            const float* Qr = Q + ((size_t)b * LL + qbase + lq) * DD;
            #pragma unroll
            for (int ds_ = 0; ds_ < 2; ++ds_) {
                const float4* p4 = reinterpret_cast<const float4*>(Qr + ds_ * 32 + lg * 8);
                float4 a = p4[0], c = p4[1];
                bf16x8 f;
                f[0] = f2bf(a.x * QSCALE); f[1] = f2bf(a.y * QSCALE);
                f[2] = f2bf(a.z * QSCALE); f[3] = f2bf(a.w * QSCALE);
                f[4] = f2bf(c.x * QSCALE); f[5] = f2bf(c.y * QSCALE);
                f[6] = f2bf(c.z * QSCALE); f[7] = f2bf(c.w * QSCALE);
                qf[ds_] = f;
            }
        }

        f32x4 acc[4];                    // acc[n][r]: q=lg*4+r, d=n*16+lq
        #pragma unroll
        for (int n = 0; n < 4; ++n) acc[n] = (f32x4){0.f, 0.f, 0.f, 0.f};
        float m_ = -1e30f, l_ = 0.f;     // scalars for q = lq

        // swapped QK^T from Buf[bi] into s[4]; conflict-free frag reads
        auto qkt = [&](int bi, f32x4* s) {
            const unsigned short* kb = &Buf[bi][0];
            __builtin_amdgcn_s_setprio(1);
            #pragma unroll
            for (int t = 0; t < 4; ++t) {
                f32x4 a = (f32x4){0.f, 0.f, 0.f, 0.f};
                #pragma unroll
                for (int ds_ = 0; ds_ < 2; ++ds_) {
                    bf16x8 kf = *reinterpret_cast<const bf16x8*>(
                        &kb[(size_t)(t * 2 + ds_) * 512 + lane * 8]);
                    a = __builtin_amdgcn_mfma_f32_16x16x32_bf16(kf, qf[ds_], a, 0, 0, 0);
                }
                s[t] = a;
            }
            __builtin_amdgcn_s_setprio(0);
        };

        // softmax(t) + PV(t): s layout s[t][r] = S[k=kt*64+t*16+lg*4+r][q=lq]
        auto smpv = [&](int kt, f32x4* s, int bi) {
            const bool tail = (kt == ntiles - 1) && (valid & (KBLK - 1));
            if (tail) {
                #pragma unroll
                for (int t = 0; t < 4; ++t)
                    #pragma unroll
                    for (int r = 0; r < 4; ++r) {
                        int kg = kt * KBLK + t * 16 + lg * 4 + r;
                        if (kg >= valid) s[t][r] = -1e30f;
                    }
            }
            float mx = s[0][0];
            #pragma unroll
            for (int t = 0; t < 4; ++t)
                #pragma unroll
                for (int r = 0; r < 4; ++r) mx = fmaxf(mx, s[t][r]);
            mx = fmaxf(mx, __shfl_xor(mx, 16, 64));
            mx = fmaxf(mx, __shfl_xor(mx, 32, 64));

            if (__any(mx - m_ > 8.0f)) {          // defer-max (T13)
                float mnew = fmaxf(m_, mx);
                float corr = exp2c(m_ - mnew);
                m_ = mnew;
                l_ *= corr;
                #pragma unroll
                for (int r = 0; r < 4; ++r) {
                    float cq = __shfl(corr, lg * 4 + r, 64);
                    #pragma unroll
                    for (int n = 0; n < 4; ++n) acc[n][r] *= cq;
                }
            }

            float ls = 0.f;
            #pragma unroll
            for (int t = 0; t < 4; ++t)
                #pragma unroll
                for (int r = 0; r < 4; ++r) {
                    float p = exp2c(s[t][r] - m_);
                    s[t][r] = p;
                    ls += p;
                }
            ls += __shfl_xor(ls, 16, 64);
            ls += __shfl_xor(ls, 32, 64);
            l_ += ls;

            // PV via 16x16x16: A = s packs (in-register), B = V-frag b64 reads
            const unsigned short* vb = &Buf[bi][4096];
            __builtin_amdgcn_s_setprio(1);
            #pragma unroll
            for (int t = 0; t < 4; ++t) {
                union { uint2 u; bf16x4 v; } pa;
                pa.u = make_uint2(pk2(s[t][0], s[t][1]), pk2(s[t][2], s[t][3]));
                #pragma unroll
                for (int n = 0; n < 4; ++n) {
                    union { uint2 u; bf16x4 v; } vv;
                    vv.u = *reinterpret_cast<const uint2*>(
                        &vb[(size_t)(n * 4 + t) * 256 + lane * 4]);
                    acc[n] = mfma16(pa.v, vv.v, acc[n]);
                }
            }
            __builtin_amdgcn_s_setprio(0);
        };

        // ---- prologue: DMA tiles 0,1; QK^T(0) -> sA
        int bc = 0, bn = 1, bd = 2;      // cur / next / dma buffer ids
        dma(0, 0);
        if (ntiles > 1) dma(1, 1);
        __syncthreads();                 // both DMAs drained
        f32x4 sA[4], sB[4];
        qkt(0, sA);

        // ---- main loop, unroll-2 (sA/sB named, rule #20)
        int t = 0;
        for (; t + 2 <= ntiles; t += 2) {
            // tile t (cur = sA)
            if (t + 2 < ntiles) dma(t + 2, bd);
            qkt(bn, sB);                 // tile t+1 (exists: t+1 < ntiles)
            smpv(t, sA, bc);
            __syncthreads();             // drains DMA(t+2); all reads of bc/bn done
            { int x = bc; bc = bn; bn = bd; bd = x; }
            // tile t+1 (cur = sB)
            if (t + 3 < ntiles) dma(t + 3, bd);
            if (t + 2 < ntiles) qkt(bn, sA);
            smpv(t + 1, sB, bc);
            __syncthreads();
            { int x = bc; bc = bn; bn = bd; bd = x; }
        }
        if (t < ntiles) smpv(t, sA, bc);   // odd tail tile

        // ---- epilogue: fetch l for q=lg*4+r via shfl, write O
        float linv[4];
        #pragma unroll
        for (int r = 0; r < 4; ++r)
            linv[r] = 1.f / __shfl(l_, lg * 4 + r, 64);
        float* Ob = O + ((size_t)b * LL + qbase) * DD;
        #pragma unroll
        for (int n = 0; n < 4; ++n) {
            #pragma unroll
            for (int r = 0; r < 4; ++r) {
                Ob[(size_t)(lg * 4 + r) * DD + n * 16 + lq] = acc[n][r] * linv[r];
            }
        }
    }
}

extern "C" void kernel_launch(void* const* d_in, const int* in_sizes, int n_in,
                              void* d_out, int out_size, void* d_ws, size_t ws_size,
                              hipStream_t stream) {
    const float* Q = (const float*)d_in[0];
    const float* K = (const float*)d_in[1];
    const float* V = (const float*)d_in[2];
    const int* vlen = (const int*)d_in[3];
    float* O = (float*)d_out;

    // ws: [0..1KB) queue; [1KB..) 16MB frag-ordered bf16 K/V images
    int* ws_i = (int*)d_ws;
    unsigned short* kvimg = (unsigned short*)((char*)d_ws + 1024);

    init_ctr_kernel<<<1, 64, 0, stream>>>(vlen, ws_i);
    convert_kv_kernel<<<BB * (LL / KBLK), 256, 0, stream>>>(K, V, kvimg);
    attn_mfma_kernel<<<GRID, 256, 0, stream>>>(Q, vlen, kvimg, O, ws_i);
}

// Round 14
// 68.967 us; speedup vs baseline: 1.1452x; 1.0790x over previous
//
#include <hip/hip_runtime.h>
#include <hip/hip_bf16.h>
#include <math.h>

// DotProductAttention B=32, L=2048, D=64, fp32 IO, per-batch key-length mask.
// Round 14: QBLK 64 -> 128 (8 waves/block). Per-tile fixed costs (DMA issue/
// drain, barrier join, queue, softmax chains) amortize over 2x the q-rows --
// the HK-shaped move (ts_qo=256 there). Per-wave core is r13 verbatim:
//  - frag-ordered bf16 K/V tile images (prepass), conflict-free ds_reads (0
//    bank conflicts measured), in-register 16x16x16 PV (no P roundtrip),
//    T15 3-buffer DMA pipeline w/ QK^T(t+1) overlap, defer-max, exp2 domain.
//  - Tickets 512 (16/batch), GRID 384 (1.33 queue slack, r6-proven ratio).
//  - LDS 48KB, 512-thr blocks -> 2 blocks/CU where doubled (4 waves/SIMD).

#define BB 32
#define LL 2048
#define DD 64
#define QBLK 128
#define KBLK 64
#define NTICKETS (BB * (LL / QBLK))   // 512
#define GRID 384

typedef __attribute__((ext_vector_type(8))) short bf16x8;
typedef __attribute__((ext_vector_type(4))) short bf16x4;
typedef __attribute__((ext_vector_type(4))) float f32x4;

static __device__ __forceinline__ short f2bf(float f) {
    __hip_bfloat16 h = __float2bfloat16(f);
    return *reinterpret_cast<short*>(&h);
}
static __device__ __forceinline__ unsigned pk2(float a, float b) {
    return (unsigned)(unsigned short)f2bf(a) | ((unsigned)(unsigned short)f2bf(b) << 16);
}
static __device__ __forceinline__ float exp2c(float x) {
    return __builtin_amdgcn_exp2f(x);
}

static __device__ __forceinline__ f32x4 mfma16(bf16x4 a, bf16x4 b, f32x4 c) {
#if __has_builtin(__builtin_amdgcn_mfma_f32_16x16x16bf16_1k)
    return __builtin_amdgcn_mfma_f32_16x16x16bf16_1k(a, b, c, 0, 0, 0);
#else
    asm("v_mfma_f32_16x16x16_bf16 %0, %1, %2, %0" : "+v"(c) : "v"(a), "v"(b));
    return c;
#endif
}

// 16B global->LDS copy. Builtin: HW DMA, LDS dst = uniform base + lane*16.
static __device__ __forceinline__ void cp16(const char* g, char* lbase, int lane) {
#if __has_builtin(__builtin_amdgcn_global_load_lds)
    __builtin_amdgcn_global_load_lds(
        (__attribute__((address_space(1))) void*)g,
        (__attribute__((address_space(3))) void*)lbase, 16, 0, 0);
#else
    *reinterpret_cast<uint4*>(lbase + lane * 16) = *reinterpret_cast<const uint4*>(g);
#endif
}

// ws[0] = queue counter; ws[1..32] = batch ids sorted by valid_len desc (LPT)
__global__ void init_ctr_kernel(const int* __restrict__ vlen, int* __restrict__ ws) {
    int t = threadIdx.x;
    if (t == 0) ws[0] = 0;
    if (t < BB) {
        int v = vlen[t];
        int rank = 0;
        for (int j = 0; j < BB; ++j) {
            int vj = vlen[j];
            rank += (vj > v) || (vj == v && j < t);
        }
        ws[1 + rank] = t;
    }
}

// K,V fp32 -> bf16 FRAGMENT-ORDERED tile images (16KB per (b,kt) tile):
//  [0,8KB):  K-frags: entry e = (t*2+ds)*64 + L holds
//            K[t*16+(L&15)][ds*32+(L>>4)*8 .. +7]  (bf16x8, 16B)
//  [8,16KB): V-frags: entry = (n*4+t)*64 + L holds
//            V[t*16+(L>>4)*4 + {0..3}][n*16+(L&15)] (bf16x4, 8B, k-ascending)
__global__ __launch_bounds__(256) void convert_kv_kernel(
    const float* __restrict__ K, const float* __restrict__ V,
    unsigned short* __restrict__ kv)
{
    const int tile = blockIdx.x;         // b*32 + kt
    const int tid  = threadIdx.x;
    const float*  Kt  = K + (size_t)tile * (KBLK * DD);
    const float4* Vg4 = reinterpret_cast<const float4*>(V + (size_t)tile * (KBLK * DD));
    unsigned short* img = kv + (size_t)tile * 8192;   // 8192 shorts = 16KB

    // K-frags: 512 x 16B entries
    #pragma unroll
    for (int g = 0; g < 2; ++g) {
        int e = tid + g * 256;
        int f = e >> 6, L = e & 63;
        int t = f >> 1, ds = f & 1;
        int lq = L & 15, lg = L >> 4;
        const float4* src = reinterpret_cast<const float4*>(
            Kt + (t * 16 + lq) * DD + ds * 32 + lg * 8);
        float4 a = src[0], c = src[1];
        uint4 w;
        w.x = pk2(a.x, a.y); w.y = pk2(a.z, a.w);
        w.z = pk2(c.x, c.y); w.w = pk2(c.z, c.w);
        *reinterpret_cast<uint4*>(img + (size_t)e * 8) = w;
    }

    // V-frags: thread owns 4k x 4d block, writes 4 x 8B entries
    unsigned short* img2 = img + 4096;
    const int vd4 = (tid & 15) * 4;
    const int vkr = (tid >> 4) * 4;
    const int vt  = vkr >> 4;            // frag t
    const int vlg = (vkr >> 2) & 3;      // frag lg
    float4 v0 = Vg4[(vkr + 0) * 16 + (tid & 15)];
    float4 v1 = Vg4[(vkr + 1) * 16 + (tid & 15)];
    float4 v2 = Vg4[(vkr + 2) * 16 + (tid & 15)];
    float4 v3 = Vg4[(vkr + 3) * 16 + (tid & 15)];
    const float* p0 = (const float*)&v0;
    const float* p1 = (const float*)&v1;
    const float* p2 = (const float*)&v2;
    const float* p3 = (const float*)&v3;
    #pragma unroll
    for (int j = 0; j < 4; ++j) {
        int col = vd4 + j;
        int n = col >> 4, lq = col & 15;
        int L = vlg * 16 + lq;
        uint2 w = make_uint2(pk2(p0[j], p1[j]), pk2(p2[j], p3[j]));
        *reinterpret_cast<uint2*>(img2 + (size_t)(n * 4 + vt) * 256 + L * 4) = w;
    }
}

__global__ __launch_bounds__(512, 1) void attn_mfma_kernel(
    const float* __restrict__ Q, const int* __restrict__ vlen,
    const unsigned short* __restrict__ kvimg,
    float* __restrict__ O, int* __restrict__ ws)
{
    __shared__ __align__(16) unsigned short Buf[3][8192];   // 3 x 16KB (K|V frags)
    __shared__ int s_tile;

    int* ctr = ws;
    const int* order = ws + 1;

    const int tid  = threadIdx.x;
    const int wid  = tid >> 6;      // 0..7
    const int lane = tid & 63;
    const int lq   = lane & 15;
    const int lg   = lane >> 4;

    const float QSCALE = 0.125f * 1.44269504088896341f;  // 1/sqrt(D) * log2(e)

    for (;;) {
        __syncthreads();                 // prev ticket fully done before reuse
        if (tid == 0) s_tile = atomicAdd(ctr, 1);
        __syncthreads();
        const int tile = s_tile;
        if (tile >= NTICKETS) break;

        const int b     = order[tile >> 4];   // LPT: longest batches first
        const int qt    = tile & 15;
        const int qbase = qt * QBLK + wid * 16;
        const int valid = vlen[b];
        const int ntiles = (valid + KBLK - 1) / KBLK;

        const unsigned short* tbase = kvimg + (size_t)b * (32 * 8192);

        // stage tile t (16KB image) into Buf[bi]: 2 x cp16 per thread
        auto dma = [&](int t, int bi) {
            const char* g = (const char*)(tbase + (size_t)t * 8192)
                            + wid * 2048 + lane * 16;
            char* l = (char*)&Buf[bi][0] + wid * 2048;
            cp16(g,        l,        lane);
            cp16(g + 1024, l + 1024, lane);
        };

        // ---- Q B-frags (regs): lane holds Q[qbase+lq][ds*32 + lg*8 .. +7]
        bf16x8 qf[2];
        {
            const float* Qr = Q + ((size_t)b * LL + qbase + lq) * DD;
            #pragma unroll
            for (int ds_ = 0; ds_ < 2; ++ds_) {
                const float4* p4 = reinterpret_cast<const float4*>(Qr + ds_ * 32 + lg * 8);
                float4 a = p4[0], c = p4[1];
                bf16x8 f;
                f[0] = f2bf(a.x * QSCALE); f[1] = f2bf(a.y * QSCALE);
                f[2] = f2bf(a.z * QSCALE); f[3] = f2bf(a.w * QSCALE);
                f[4] = f2bf(c.x * QSCALE); f[5] = f2bf(c.y * QSCALE);
                f[6] = f2bf(c.z * QSCALE); f[7] = f2bf(c.w * QSCALE);
                qf[ds_] = f;
            }
        }

        f32x4 acc[4];                    // acc[n][r]: q=lg*4+r, d=n*16+lq
        #pragma unroll
        for (int n = 0; n < 4; ++n) acc[n] = (f32x4){0.f, 0.f, 0.f, 0.f};
        float m_ = -1e30f, l_ = 0.f;     // scalars for q = lq

        // swapped QK^T from Buf[bi] into s[4]; conflict-free frag reads
        auto qkt = [&](int bi, f32x4* s) {
            const unsigned short* kb = &Buf[bi][0];
            __builtin_amdgcn_s_setprio(1);
            #pragma unroll
            for (int t = 0; t < 4; ++t) {
                f32x4 a = (f32x4){0.f, 0.f, 0.f, 0.f};
                #pragma unroll
                for (int ds_ = 0; ds_ < 2; ++ds_) {
                    bf16x8 kf = *reinterpret_cast<const bf16x8*>(
                        &kb[(size_t)(t * 2 + ds_) * 512 + lane * 8]);
                    a = __builtin_amdgcn_mfma_f32_16x16x32_bf16(kf, qf[ds_], a, 0, 0, 0);
                }
                s[t] = a;
            }
            __builtin_amdgcn_s_setprio(0);
        };

        // softmax(t) + PV(t): s layout s[t][r] = S[k=kt*64+t*16+lg*4+r][q=lq]
        auto smpv = [&](int kt, f32x4* s, int bi) {
            const bool tail = (kt == ntiles - 1) && (valid & (KBLK - 1));
            if (tail) {
                #pragma unroll
                for (int t = 0; t < 4; ++t)
                    #pragma unroll
                    for (int r = 0; r < 4; ++r) {
                        int kg = kt * KBLK + t * 16 + lg * 4 + r;
                        if (kg >= valid) s[t][r] = -1e30f;
                    }
            }
            float mx = s[0][0];
            #pragma unroll
            for (int t = 0; t < 4; ++t)
                #pragma unroll
                for (int r = 0; r < 4; ++r) mx = fmaxf(mx, s[t][r]);
            mx = fmaxf(mx, __shfl_xor(mx, 16, 64));
            mx = fmaxf(mx, __shfl_xor(mx, 32, 64));

            if (__any(mx - m_ > 8.0f)) {          // defer-max (T13)
                float mnew = fmaxf(m_, mx);
                float corr = exp2c(m_ - mnew);
                m_ = mnew;
                l_ *= corr;
                #pragma unroll
                for (int r = 0; r < 4; ++r) {
                    float cq = __shfl(corr, lg * 4 + r, 64);
                    #pragma unroll
                    for (int n = 0; n < 4; ++n) acc[n][r] *= cq;
                }
            }

            float ls = 0.f;
            #pragma unroll
            for (int t = 0; t < 4; ++t)
                #pragma unroll
                for (int r = 0; r < 4; ++r) {
                    float p = exp2c(s[t][r] - m_);
                    s[t][r] = p;
                    ls += p;
                }
            ls += __shfl_xor(ls, 16, 64);
            ls += __shfl_xor(ls, 32, 64);
            l_ += ls;

            // PV via 16x16x16: A = s packs (in-register), B = V-frag b64 reads
            const unsigned short* vb = &Buf[bi][4096];
            __builtin_amdgcn_s_setprio(1);
            #pragma unroll
            for (int t = 0; t < 4; ++t) {
                union { uint2 u; bf16x4 v; } pa;
                pa.u = make_uint2(pk2(s[t][0], s[t][1]), pk2(s[t][2], s[t][3]));
                #pragma unroll
                for (int n = 0; n < 4; ++n) {
                    union { uint2 u; bf16x4 v; } vv;
                    vv.u = *reinterpret_cast<const uint2*>(
                        &vb[(size_t)(n * 4 + t) * 256 + lane * 4]);
                    acc[n] = mfma16(pa.v, vv.v, acc[n]);
                }
            }
            __builtin_amdgcn_s_setprio(0);
        };

        // ---- prologue: DMA tiles 0,1; QK^T(0) -> sA
        int bc = 0, bn = 1, bd = 2;      // cur / next / dma buffer ids
        dma(0, 0);
        if (ntiles > 1) dma(1, 1);
        __syncthreads();                 // both DMAs drained
        f32x4 sA[4], sB[4];
        qkt(0, sA);

        // ---- main loop, unroll-2 (sA/sB named, rule #20)
        int t = 0;
        for (; t + 2 <= ntiles; t += 2) {
            // tile t (cur = sA)
            if (t + 2 < ntiles) dma(t + 2, bd);
            qkt(bn, sB);                 // tile t+1 (exists: t+1 < ntiles)
            smpv(t, sA, bc);
            __syncthreads();             // drains DMA(t+2); all reads of bc/bn done
            { int x = bc; bc = bn; bn = bd; bd = x; }
            // tile t+1 (cur = sB)
            if (t + 3 < ntiles) dma(t + 3, bd);
            if (t + 2 < ntiles) qkt(bn, sA);
            smpv(t + 1, sB, bc);
            __syncthreads();
            { int x = bc; bc = bn; bn = bd; bd = x; }
        }
        if (t < ntiles) smpv(t, sA, bc);   // odd tail tile

        // ---- epilogue: fetch l for q=lg*4+r via shfl, write O
        float linv[4];
        #pragma unroll
        for (int r = 0; r < 4; ++r)
            linv[r] = 1.f / __shfl(l_, lg * 4 + r, 64);
        float* Ob = O + ((size_t)b * LL + qbase) * DD;
        #pragma unroll
        for (int n = 0; n < 4; ++n) {
            #pragma unroll
            for (int r = 0; r < 4; ++r) {
                Ob[(size_t)(lg * 4 + r) * DD + n * 16 + lq] = acc[n][r] * linv[r];
            }
        }
    }
}

extern "C" void kernel_launch(void* const* d_in, const int* in_sizes, int n_in,
                              void* d_out, int out_size, void* d_ws, size_t ws_size,
                              hipStream_t stream) {
    const float* Q = (const float*)d_in[0];
    const float* K = (const float*)d_in[1];
    const float* V = (const float*)d_in[2];
    const int* vlen = (const int*)d_in[3];
    float* O = (float*)d_out;

    // ws: [0..1KB) queue; [1KB..) 16MB frag-ordered bf16 K/V images
    int* ws_i = (int*)d_ws;
    unsigned short* kvimg = (unsigned short*)((char*)d_ws + 1024);

    init_ctr_kernel<<<1, 64, 0, stream>>>(vlen, ws_i);
    convert_kv_kernel<<<BB * (LL / KBLK), 256, 0, stream>>>(K, V, kvimg);
    attn_mfma_kernel<<<GRID, 512, 0, stream>>>(Q, vlen, kvimg, O, ws_i);
}